// Round 5
// baseline (186.757 us; speedup 1.0000x reference)
//
#include <hip/hip_runtime.h>
#include <hip/hip_bf16.h>
#include <stdint.h>

#define N_TOK 8192
#define D_K   1024
#define BM    256
#define BN    256
#define BK    32
#define NT    (D_K / BK)            // 32 K-tiles
#define TILE_E (BM * BK)            // 8192 elems = 16 KB per operand tile

typedef __attribute__((ext_vector_type(8))) short bf16x8;
typedef __attribute__((ext_vector_type(4))) float f32x4;

__global__ void zero_out_kernel(float* out) { out[0] = 0.0f; }

__device__ __forceinline__ unsigned short f32_to_bf16_rne(float x) {
  uint32_t u = __builtin_bit_cast(uint32_t, x);
  uint32_t r = (u >> 16) & 1u;
  u += 0x7fffu + r;
  return (unsigned short)(u >> 16);
}

__global__ void __launch_bounds__(256)
convert_kernel(const float* __restrict__ a, const float* __restrict__ b,
               ushort* __restrict__ oa, ushort* __restrict__ ob) {
  const size_t total4 = (size_t)N_TOK * D_K / 4;
  size_t i = (size_t)blockIdx.x * blockDim.x + threadIdx.x;
  size_t stride = (size_t)gridDim.x * blockDim.x;
  for (; i < total4; i += stride) {
    float4 va = ((const float4*)a)[i];
    float4 vb = ((const float4*)b)[i];
    ushort4 ua, ub;
    ua.x = f32_to_bf16_rne(va.x); ua.y = f32_to_bf16_rne(va.y);
    ua.z = f32_to_bf16_rne(va.z); ua.w = f32_to_bf16_rne(va.w);
    ub.x = f32_to_bf16_rne(vb.x); ub.y = f32_to_bf16_rne(vb.y);
    ub.z = f32_to_bf16_rne(vb.z); ub.w = f32_to_bf16_rne(vb.w);
    ((ushort4*)oa)[i] = ua;
    ((ushort4*)ob)[i] = ub;
  }
}

// Fused 256x256 bf16 MFMA GEMM + sigmoid-contrastive loss.
// BK=32, ring-4 LDS per operand, stage lead 3 tiles, counted vmcnt (T4).
// Register-pipelined fragments one phase ahead: every 16-MFMA burst has
// the next phase's ds_reads (and gloads) in flight beneath it (counted
// lgkm waits emitted by the compiler). 2 barriers per tile.
__global__ void __launch_bounds__(512)
sigc_kernel(const ushort* __restrict__ A, const ushort* __restrict__ B,
            const int* __restrict__ labA, const int* __restrict__ labB,
            const float* __restrict__ scale_p, const float* __restrict__ bias_p,
            float* __restrict__ out) {
  __shared__ ushort sA[4 * TILE_E];   // 64 KB
  __shared__ ushort sB[4 * TILE_E];   // 64 KB
  __shared__ int sLabA[BM];
  __shared__ int sLabB[BN];
  __shared__ float sPart[8];

  const int tid  = threadIdx.x;
  const int lane = tid & 63;
  const int wid  = tid >> 6;      // 0..7
  const int wr   = wid >> 2;      // 0..1 (M half)
  const int wc   = wid & 3;       // 0..3 (N quarter)
  const int lr   = lane & 15;
  const int sHi  = lane >> 4;     // 0..3 (16B slot)

  // XCD-aware block swizzle: grid = 1024 (divisible by 8).
  const int bid  = (int)blockIdx.x;
  const int swzb = (bid & 7) * 128 + (bid >> 3);
  const int bRow = (swzb >> 5) * BM;
  const int bCol = (swzb & 31) * BN;

  if (tid < 256) sLabA[tid] = labA[bRow + tid];
  else           sLabB[tid - 256] = labB[bCol + (tid - 256)];

  // Staging geometry (rule #21): linear LDS dest, swizzled global source.
  int sgRow[2], sgCol[2];
#pragma unroll
  for (int i = 0; i < 2; ++i) {
    const int e    = i * 4096 + tid * 8;
    const int row  = e >> 5;
    const int slot = (e >> 3) & 3;
    sgRow[i] = row;
    sgCol[i] = (slot ^ ((row >> 1) & 3)) << 3;
  }
  const int ldsOff0 = wid * 512;
  const int ldsOff1 = 4096 + wid * 512;

  auto stageA = [&](int tt) {
    ushort* d = sA + (tt & 3) * TILE_E;
    const ushort* g0 = A + (size_t)(bRow + sgRow[0]) * D_K + tt * BK + sgCol[0];
    const ushort* g1 = A + (size_t)(bRow + sgRow[1]) * D_K + tt * BK + sgCol[1];
    __builtin_amdgcn_global_load_lds(
        (const __attribute__((address_space(1))) void*)g0,
        (__attribute__((address_space(3))) void*)(d + ldsOff0), 16, 0, 0);
    __builtin_amdgcn_global_load_lds(
        (const __attribute__((address_space(1))) void*)g1,
        (__attribute__((address_space(3))) void*)(d + ldsOff1), 16, 0, 0);
  };
  auto stageB = [&](int tt) {
    ushort* d = sB + (tt & 3) * TILE_E;
    const ushort* g0 = B + (size_t)(bCol + sgRow[0]) * D_K + tt * BK + sgCol[0];
    const ushort* g1 = B + (size_t)(bCol + sgRow[1]) * D_K + tt * BK + sgCol[1];
    __builtin_amdgcn_global_load_lds(
        (const __attribute__((address_space(1))) void*)g0,
        (__attribute__((address_space(3))) void*)(d + ldsOff0), 16, 0, 0);
    __builtin_amdgcn_global_load_lds(
        (const __attribute__((address_space(1))) void*)g1,
        (__attribute__((address_space(3))) void*)(d + ldsOff1), 16, 0, 0);
  };

  // Tile-invariant fragment byte-offsets (swizzled).
  int offA0[4], offA1[4], offB[4];
#pragma unroll
  for (int mi = 0; mi < 4; ++mi) {
    {
      const int r = wr * 128 + mi * 16 + lr;
      offA0[mi] = r * BK + ((sHi ^ ((r >> 1) & 3)) << 3);
    }
    {
      const int r = wr * 128 + 64 + mi * 16 + lr;
      offA1[mi] = r * BK + ((sHi ^ ((r >> 1) & 3)) << 3);
    }
    {
      const int r = wc * 64 + mi * 16 + lr;
      offB[mi] = r * BK + ((sHi ^ ((r >> 1) & 3)) << 3);
    }
  }

  f32x4 acc[2][4][4];
#pragma unroll
  for (int q = 0; q < 2; ++q)
#pragma unroll
    for (int i = 0; i < 4; ++i)
#pragma unroll
      for (int j = 0; j < 4; ++j) acc[q][i][j] = (f32x4){0.f, 0.f, 0.f, 0.f};

  // Prologue: stage tiles 0..2; full drain (publishes labels + tile 0..2).
  stageA(0); stageB(0);
  stageA(1); stageB(1);
  stageA(2); stageB(2);
  __syncthreads();

  // Pre-read phase-A fragments of tile 0.
  bf16x8 af[4], bf[4], ag[4];
#pragma unroll
  for (int mi = 0; mi < 4; ++mi) {
    af[mi] = *(const bf16x8*)&sA[offA0[mi]];
    bf[mi] = *(const bf16x8*)&sB[offB[mi]];
  }

  for (int t = 0; t < NT; ++t) {
    const ushort* bufA = sA + (t & 3) * TILE_E;
    const ushort* bufB = sB + (t & 3) * TILE_E;
    const ushort* nxtA = sA + ((t + 1) & 3) * TILE_E;
    const ushort* nxtB = sB + ((t + 1) & 3) * TILE_E;

    // ---- phase A: issue ag reads + stage; MFMA over (af,bf) ----
#pragma unroll
    for (int mi = 0; mi < 4; ++mi)
      ag[mi] = *(const bf16x8*)&bufA[offA1[mi]];
    if (t <= NT - 4) { stageA(t + 3); stageB(t + 3); }
    __builtin_amdgcn_s_setprio(1);
#pragma unroll
    for (int mi = 0; mi < 4; ++mi)
#pragma unroll
      for (int ni = 0; ni < 4; ++ni)
        acc[0][mi][ni] = __builtin_amdgcn_mfma_f32_16x16x32_bf16(
            af[mi], bf[ni], acc[0][mi][ni], 0, 0, 0);
    __builtin_amdgcn_s_setprio(0);

    // mid-tile: retire stage(t+1), publish cross-wave.
    if (t < NT - 1) {
      if (t <= NT - 4)      asm volatile("s_waitcnt vmcnt(8)" ::: "memory");
      else if (t == NT - 3) asm volatile("s_waitcnt vmcnt(4)" ::: "memory");
      else                  asm volatile("s_waitcnt vmcnt(0)" ::: "memory");
      __builtin_amdgcn_sched_barrier(0);
      __builtin_amdgcn_s_barrier();
      __builtin_amdgcn_sched_barrier(0);
    }

    // ---- phase B: issue af' reads; MFMA over (ag,bf); issue bf' reads ----
    if (t < NT - 1) {
#pragma unroll
      for (int mi = 0; mi < 4; ++mi)
        af[mi] = *(const bf16x8*)&nxtA[offA0[mi]];
    }
    __builtin_amdgcn_s_setprio(1);
#pragma unroll
    for (int mi = 0; mi < 4; ++mi)
#pragma unroll
      for (int ni = 0; ni < 4; ++ni)
        acc[1][mi][ni] = __builtin_amdgcn_mfma_f32_16x16x32_bf16(
            ag[mi], bf[ni], acc[1][mi][ni], 0, 0, 0);
    __builtin_amdgcn_s_setprio(0);
    if (t < NT - 1) {
#pragma unroll
      for (int mi = 0; mi < 4; ++mi)
        bf[mi] = *(const bf16x8*)&nxtB[offB[mi]];
      __builtin_amdgcn_sched_barrier(0);
      __builtin_amdgcn_s_barrier();
      __builtin_amdgcn_sched_barrier(0);
    }
  }

  // Epilogue: -log_sigmoid(label*logit) = max(t,0) + log(1+exp(-|t|)).
  const float scale = scale_p[0];
  const float bias  = bias_p[0];
  float loss = 0.0f;
  const int cBase = lane & 15;
  const int rBase = (lane >> 4) * 4;
#pragma unroll
  for (int mh = 0; mh < 2; ++mh) {
#pragma unroll
    for (int mi = 0; mi < 4; ++mi) {
#pragma unroll
      for (int ni = 0; ni < 4; ++ni) {
        const int colL = sLabB[wc * 64 + ni * 16 + cBase];
#pragma unroll
        for (int r = 0; r < 4; ++r) {
          const int rowL = sLabA[wr * 128 + mh * 64 + mi * 16 + rBase + r];
          const float logit = fmaf(scale, acc[mh][mi][ni][r], bias);
          const float tt = (rowL == colL) ? -logit : logit;
          loss += fmaxf(tt, 0.0f) + __logf(1.0f + __expf(-fabsf(tt)));
        }
      }
    }
  }

#pragma unroll
  for (int off = 32; off > 0; off >>= 1) loss += __shfl_down(loss, off, 64);
  if (lane == 0) sPart[wid] = loss;
  __syncthreads();
  if (tid == 0) {
    float s = 0.f;
#pragma unroll
    for (int w = 0; w < 8; ++w) s += sPart[w];
    atomicAdd(out, s * (1.0f / (float)N_TOK));
  }
}

extern "C" void kernel_launch(void* const* d_in, const int* in_sizes, int n_in,
                              void* d_out, int out_size, void* d_ws, size_t ws_size,
                              hipStream_t stream) {
  const float* a  = (const float*)d_in[0];
  const float* b  = (const float*)d_in[1];
  const int*   la = (const int*)d_in[2];
  const int*   lb = (const int*)d_in[3];
  const float* sc = (const float*)d_in[4];
  const float* bi = (const float*)d_in[5];
  float* out = (float*)d_out;

  ushort* wa = (ushort*)d_ws;                       // bf16 A, 16 MB
  ushort* wb = wa + (size_t)N_TOK * D_K;            // bf16 B, 16 MB

  zero_out_kernel<<<1, 1, 0, stream>>>(out);
  convert_kernel<<<2048, 256, 0, stream>>>(a, b, wa, wb);
  const int grid = (N_TOK / BM) * (N_TOK / BN);     // 1024
  sigc_kernel<<<grid, 512, 0, stream>>>(wa, wb, la, lb, sc, bi, out);
}

// Round 6
// 183.266 us; speedup vs baseline: 1.0191x; 1.0191x over previous
//
#include <hip/hip_runtime.h>
#include <hip/hip_bf16.h>
#include <stdint.h>

#define N_TOK 8192
#define D_K   1024
#define BM    256
#define BN    256
#define BK    64
#define NT    (D_K / BK)            // 16 K-tiles, 8 iterations x 2
#define HALF_E (128 * BK)           // 8192 elems = 16 KB per half-tile

typedef __attribute__((ext_vector_type(8))) short bf16x8;
typedef __attribute__((ext_vector_type(4))) float f32x4;

__global__ void zero_out_kernel(float* out) { out[0] = 0.0f; }

__device__ __forceinline__ unsigned short f32_to_bf16_rne(float x) {
  uint32_t u = __builtin_bit_cast(uint32_t, x);
  uint32_t r = (u >> 16) & 1u;
  u += 0x7fffu + r;
  return (unsigned short)(u >> 16);
}

__global__ void __launch_bounds__(256)
convert_kernel(const float* __restrict__ a, const float* __restrict__ b,
               ushort* __restrict__ oa, ushort* __restrict__ ob) {
  const size_t total4 = (size_t)N_TOK * D_K / 4;
  size_t i = (size_t)blockIdx.x * blockDim.x + threadIdx.x;
  size_t stride = (size_t)gridDim.x * blockDim.x;
  for (; i < total4; i += stride) {
    float4 va = ((const float4*)a)[i];
    float4 vb = ((const float4*)b)[i];
    ushort4 ua, ub;
    ua.x = f32_to_bf16_rne(va.x); ua.y = f32_to_bf16_rne(va.y);
    ua.z = f32_to_bf16_rne(va.z); ua.w = f32_to_bf16_rne(va.w);
    ub.x = f32_to_bf16_rne(vb.x); ub.y = f32_to_bf16_rne(vb.y);
    ub.z = f32_to_bf16_rne(vb.z); ub.w = f32_to_bf16_rne(vb.w);
    ((ushort4*)oa)[i] = ua;
    ((ushort4*)ob)[i] = ub;
  }
}

// Fused 256x256 bf16 MFMA GEMM + sigmoid-contrastive loss.
// m201-style 8-phase schedule: BK=64, dbuf x 2 halves per operand (128 KB),
// per phase {ds-reads, 2 global_load_lds, [vmcnt], barrier, lgkmcnt(0),
// setprio, 16 MFMA, setprio, barrier}. vmcnt(6) only at phases 3 and 7.
__global__ void __launch_bounds__(512, 2)
sigc_kernel(const ushort* __restrict__ A, const ushort* __restrict__ B,
            const int* __restrict__ labA, const int* __restrict__ labB,
            const float* __restrict__ scale_p, const float* __restrict__ bias_p,
            float* __restrict__ out) {
  // index: [op(A=0,B=1)<<2 | parity<<1 | half]
  __shared__ ushort sTile[8][HALF_E];     // 128 KB
  __shared__ int sLabA[BM];
  __shared__ int sLabB[BN];
  __shared__ float sPart[8];

  const int tid  = threadIdx.x;
  const int lane = tid & 63;
  const int wid  = tid >> 6;      // 0..7
  const int wr   = wid >> 2;      // 0..1 (M half: rows wr*128..)
  const int wc   = wid & 3;       // 0..3 (N quarter: cols wc*64..)
  const int lr   = lane & 15;
  const int sHi  = lane >> 4;     // 0..3

  // T1: XCD-aware block swizzle (grid 1024, %8==0).
  const int bid  = (int)blockIdx.x;
  const int swzb = (bid & 7) * 128 + (bid >> 3);
  const int bRow = (swzb >> 5) * BM;
  const int bCol = (swzb & 31) * BN;

  if (tid < 256) sLabA[tid] = labA[bRow + tid];
  else           sLabB[tid - 256] = labB[bCol + (tid - 256)];

  // T2 (rule #21): linear LDS dest, XOR-swizzled global source column.
  auto stage = [&](const ushort* __restrict__ G, int gBase, int op,
                   int tile, int half, int ld) {
    const int par = tile & 1;
    ushort* d = &sTile[(op << 2) | (par << 1) | half][ld * 4096 + wid * 512];
    const int e    = ld * 4096 + tid * 8;
    const int row  = e >> 6;                    // 0..127 within half
    const int slot = (e >> 3) & 7;
    const int col  = (slot ^ (row & 7)) << 3;
    const ushort* g = G + (size_t)(gBase + half * 128 + row) * D_K
                        + tile * BK + col;
    __builtin_amdgcn_global_load_lds(
        (const __attribute__((address_space(1))) void*)g,
        (__attribute__((address_space(3))) void*)d, 16, 0, 0);
  };

  auto rdA = [&](int par, int ms, bf16x8 a[4][2]) {
    const ushort* p = sTile[(0 << 2) | (par << 1) | wr];
#pragma unroll
    for (int mf = 0; mf < 4; ++mf)
#pragma unroll
      for (int ks = 0; ks < 2; ++ks) {
        const int r = ms * 64 + mf * 16 + lr;
        const int s = ks * 4 + sHi;
        a[mf][ks] = *(const bf16x8*)&p[r * BK + ((s ^ (r & 7)) << 3)];
      }
  };
  auto rdB = [&](int par, int ns, bf16x8 b[2][2]) {
    const ushort* p = sTile[(1 << 2) | (par << 1) | (wc >> 1)];
#pragma unroll
    for (int nf = 0; nf < 2; ++nf)
#pragma unroll
      for (int ks = 0; ks < 2; ++ks) {
        const int r = (wc & 1) * 64 + ns * 32 + nf * 16 + lr;
        const int s = ks * 4 + sHi;
        b[nf][ks] = *(const bf16x8*)&p[r * BK + ((s ^ (r & 7)) << 3)];
      }
  };

  f32x4 acc[8][4];
#pragma unroll
  for (int i = 0; i < 8; ++i)
#pragma unroll
    for (int j = 0; j < 4; ++j) acc[i][j] = (f32x4){0.f, 0.f, 0.f, 0.f};

  auto mmaq = [&](int ms, int ns, bf16x8 a[4][2], bf16x8 b[2][2]) {
    __builtin_amdgcn_s_setprio(1);
#pragma unroll
    for (int ks = 0; ks < 2; ++ks)
#pragma unroll
      for (int mf = 0; mf < 4; ++mf)
#pragma unroll
        for (int nf = 0; nf < 2; ++nf)
          acc[ms * 4 + mf][ns * 2 + nf] =
              __builtin_amdgcn_mfma_f32_16x16x32_bf16(
                  a[mf][ks], b[nf][ks], acc[ms * 4 + mf][ns * 2 + nf], 0, 0, 0);
    __builtin_amdgcn_s_setprio(0);
  };

  auto syncMid = [&]() {
    __builtin_amdgcn_sched_barrier(0);
    __builtin_amdgcn_s_barrier();
    asm volatile("s_waitcnt lgkmcnt(0)" ::: "memory");
    __builtin_amdgcn_sched_barrier(0);
  };
  auto syncEnd = [&]() {
    __builtin_amdgcn_sched_barrier(0);
    __builtin_amdgcn_s_barrier();
  };

  // Prologue: tile 0 fully (8 loads) + tile 1's [A.l0 x2, B x4] (6 loads).
  stage(A, bRow, 0, 0, 0, 0); stage(A, bRow, 0, 0, 0, 1);
  stage(A, bRow, 0, 0, 1, 0); stage(A, bRow, 0, 0, 1, 1);
  stage(B, bCol, 1, 0, 0, 0); stage(B, bCol, 1, 0, 0, 1);
  stage(B, bCol, 1, 0, 1, 0); stage(B, bCol, 1, 0, 1, 1);
  stage(A, bRow, 0, 1, 0, 0); stage(A, bRow, 0, 1, 1, 0);
  stage(B, bCol, 1, 1, 0, 0); stage(B, bCol, 1, 1, 0, 1);
  stage(B, bCol, 1, 1, 1, 0); stage(B, bCol, 1, 1, 1, 1);
  asm volatile("s_waitcnt vmcnt(6)" ::: "memory");   // tile 0 landed
  __syncthreads();

  bf16x8 af[4][2], bf0[2][2], bf1[2][2];

  for (int t2 = 0; t2 < NT / 2; ++t2) {
    const int e = 2 * t2, o = e + 1;
    const bool more = (t2 < NT / 2 - 1);

    // p0: quadrant (0,0) of tile e; stage A.l1(o).
    rdA(0, 0, af); rdB(0, 0, bf0);
    stage(A, bRow, 0, o, 0, 1); stage(A, bRow, 0, o, 1, 1);
    syncMid(); mmaq(0, 0, af, bf0); syncEnd();

    // p1: (0,1); stage A.l0(e+2).
    rdB(0, 1, bf1);
    if (more) { stage(A, bRow, 0, e + 2, 0, 0); stage(A, bRow, 0, e + 2, 1, 0); }
    syncMid(); mmaq(0, 1, af, bf1); syncEnd();

    // p2: (1,1); stage B0(e+2).
    rdA(0, 1, af);
    if (more) { stage(B, bCol, 1, e + 2, 0, 0); stage(B, bCol, 1, e + 2, 0, 1); }
    syncMid(); mmaq(1, 1, af, bf1); syncEnd();

    // p3: (1,0); stage B1(e+2); counted vmcnt -> tile o fully landed.
    if (more) { stage(B, bCol, 1, e + 2, 1, 0); stage(B, bCol, 1, e + 2, 1, 1); }
    if (more) asm volatile("s_waitcnt vmcnt(6)" ::: "memory");
    else      asm volatile("s_waitcnt vmcnt(0)" ::: "memory");
    syncMid(); mmaq(1, 0, af, bf0); syncEnd();

    // p4: quadrant (0,0) of tile o; stage A.l1(e+2).
    rdA(1, 0, af); rdB(1, 0, bf0);
    if (more) { stage(A, bRow, 0, e + 2, 0, 1); stage(A, bRow, 0, e + 2, 1, 1); }
    syncMid(); mmaq(0, 0, af, bf0); syncEnd();

    // p5: (0,1); stage A.l0(o+2).
    rdB(1, 1, bf1);
    if (more) { stage(A, bRow, 0, o + 2, 0, 0); stage(A, bRow, 0, o + 2, 1, 0); }
    syncMid(); mmaq(0, 1, af, bf1); syncEnd();

    // p6: (1,1); stage B0(o+2).
    rdA(1, 1, af);
    if (more) { stage(B, bCol, 1, o + 2, 0, 0); stage(B, bCol, 1, o + 2, 0, 1); }
    syncMid(); mmaq(1, 1, af, bf1); syncEnd();

    // p7: (1,0); stage B1(o+2); counted vmcnt -> tile e+2 fully landed.
    if (more) { stage(B, bCol, 1, o + 2, 1, 0); stage(B, bCol, 1, o + 2, 1, 1); }
    if (more) asm volatile("s_waitcnt vmcnt(6)" ::: "memory");
    syncMid(); mmaq(1, 0, af, bf0); syncEnd();
  }

  // Epilogue: -log_sigmoid(label*logit) = max(t,0) + log(1+exp(-|t|)).
  const float scale = scale_p[0];
  const float bias  = bias_p[0];
  float loss = 0.0f;
  const int cBase = lane & 15;
  const int rBase = (lane >> 4) * 4;
#pragma unroll
  for (int ms = 0; ms < 2; ++ms)
#pragma unroll
    for (int mf = 0; mf < 4; ++mf)
#pragma unroll
      for (int ns = 0; ns < 2; ++ns)
#pragma unroll
        for (int nf = 0; nf < 2; ++nf) {
          const int colL = sLabB[wc * 64 + ns * 32 + nf * 16 + cBase];
#pragma unroll
          for (int r = 0; r < 4; ++r) {
            const int rowL = sLabA[wr * 128 + ms * 64 + mf * 16 + rBase + r];
            const float logit =
                fmaf(scale, acc[ms * 4 + mf][ns * 2 + nf][r], bias);
            const float tt = (rowL == colL) ? -logit : logit;
            loss += fmaxf(tt, 0.0f) + __logf(1.0f + __expf(-fabsf(tt)));
          }
        }

#pragma unroll
  for (int off = 32; off > 0; off >>= 1) loss += __shfl_down(loss, off, 64);
  if (lane == 0) sPart[wid] = loss;
  __syncthreads();
  if (tid == 0) {
    float s = 0.f;
#pragma unroll
    for (int w = 0; w < 8; ++w) s += sPart[w];
    atomicAdd(out, s * (1.0f / (float)N_TOK));
  }
}

extern "C" void kernel_launch(void* const* d_in, const int* in_sizes, int n_in,
                              void* d_out, int out_size, void* d_ws, size_t ws_size,
                              hipStream_t stream) {
  const float* a  = (const float*)d_in[0];
  const float* b  = (const float*)d_in[1];
  const int*   la = (const int*)d_in[2];
  const int*   lb = (const int*)d_in[3];
  const float* sc = (const float*)d_in[4];
  const float* bi = (const float*)d_in[5];
  float* out = (float*)d_out;

  ushort* wa = (ushort*)d_ws;                       // bf16 A, 16 MB
  ushort* wb = wa + (size_t)N_TOK * D_K;            // bf16 B, 16 MB

  zero_out_kernel<<<1, 1, 0, stream>>>(out);
  convert_kernel<<<2048, 256, 0, stream>>>(a, b, wa, wb);
  const int grid = (N_TOK / BM) * (N_TOK / BN);     // 1024
  sigc_kernel<<<grid, 512, 0, stream>>>(wa, wb, la, lb, sc, bi, out);
}